// Round 4
// baseline (139.176 us; speedup 1.0000x reference)
//
#include <hip/hip_runtime.h>

#define NPRI 10647
#define BB 16
#define LL 50
#define ASS_BLOCKS (BB * LL)                 // 800 assign blocks (one per label)
#define OBJ_BLOCKS 720                       // 48 (L0) + 144 (L1) + 528 (L2)
#define A_BLOCKS (ASS_BLOCKS + OBJ_BLOCKS)   // 1520: fused assign + obj-base
#define CHO_BLOCKS (BB * LL)                 // 800

// 0.5 - 2^-26: exact post-rounding threshold. round_rn(inter/denom) >= 0.5f
// <=> inter >= denom * SUPP_C (significand product exact in double; tie at
// 0.5-2^-26 rounds to even = 0.5 => suppressed). Validated earlier sessions.
#define SUPP_C 0.49999998509883880615234375

// ---- compile-time anchor constants (numpy python-float math) ----
constexpr double HWd[3][3] = {
    {0.5*(116.0/416.0), 0.5*(156.0/416.0), 0.5*(373.0/416.0)},
    {0.5*( 30.0/416.0), 0.5*( 62.0/416.0), 0.5*( 59.0/416.0)},
    {0.5*( 10.0/416.0), 0.5*( 16.0/416.0), 0.5*( 33.0/416.0)}};
constexpr double HHd[3][3] = {
    {0.5*( 90.0/416.0), 0.5*(198.0/416.0), 0.5*(326.0/416.0)},
    {0.5*( 61.0/416.0), 0.5*( 45.0/416.0), 0.5*(119.0/416.0)},
    {0.5*( 23.0/416.0), 0.5*( 30.0/416.0), 0.5*( 23.0/416.0)}};
constexpr float PWf[3][3] = {
    {(float)(116.0/416.0), (float)(156.0/416.0), (float)(373.0/416.0)},
    {(float)( 30.0/416.0), (float)( 62.0/416.0), (float)( 59.0/416.0)},
    {(float)( 10.0/416.0), (float)( 16.0/416.0), (float)( 33.0/416.0)}};
constexpr float PHf[3][3] = {
    {(float)( 90.0/416.0), (float)(198.0/416.0), (float)(326.0/416.0)},
    {(float)( 61.0/416.0), (float)( 45.0/416.0), (float)(119.0/416.0)},
    {(float)( 23.0/416.0), (float)( 30.0/416.0), (float)( 23.0/416.0)}};

// Entire 273-entry (level,aa,idx) prior table baked at COMPILE TIME — clang
// constexpr fp math is IEEE RN, bitwise-identical to the old runtime
// f64-div + __fadd_rn sequence. No runtime f64 divides remain anywhere.
struct PTab { float px[273], pxe[273], py[273], pye[273]; };
constexpr PTab make_ptab() {
    PTab t{};
    for (int tt = 0; tt < 273; ++tt) {
        int level, aa, idx;
        if (tt < 39)       { level = 0; aa = tt / 13;           idx = tt - 13 * aa; }
        else if (tt < 117) { level = 1; int q = tt - 39;  aa = q / 26; idx = q - 26 * aa; }
        else               { level = 2; int q = tt - 117; aa = q / 52; idx = q - 52 * aa; }
        int S = (level == 0) ? 13 : (level == 1) ? 26 : 52;
        double c = ((double)idx + 0.5) / (double)S;   // numpy-exact
        float px = (float)(c - HWd[level][aa]);
        float py = (float)(c - HHd[level][aa]);
        t.px[tt] = px; t.pxe[tt] = px + PWf[level][aa];
        t.py[tt] = py; t.pye[tt] = py + PHf[level][aa];
    }
    return t;
}
__device__ __constant__ PTab g_ptab = make_ptab();

// pw*ph folded at compile time (float x float, IEEE RN == __fmul_rn)
__device__ __constant__ float c_pwph[3][3] = {
    {(float)(116.0/416.0)*(float)( 90.0/416.0), (float)(156.0/416.0)*(float)(198.0/416.0), (float)(373.0/416.0)*(float)(326.0/416.0)},
    {(float)( 30.0/416.0)*(float)( 61.0/416.0), (float)( 62.0/416.0)*(float)( 45.0/416.0), (float)( 59.0/416.0)*(float)(119.0/416.0)},
    {(float)( 10.0/416.0)*(float)( 23.0/416.0), (float)( 16.0/416.0)*(float)( 30.0/416.0), (float)( 33.0/416.0)*(float)( 23.0/416.0)}};
__device__ __constant__ float c_awf[3][3] = {{116,156,373},{30,62,59},{10,16,33}};
__device__ __constant__ float c_ahf[3][3] = {{90,198,326},{61,45,119},{23,30,23}};
// 1 / (B*A*S*S) per level
__device__ __constant__ double c_wObj[3] = {1.0/8112.0, 1.0/32448.0, 1.0/129792.0};

// decode prior n -> level,S,ii,jj,aa and base of the 273-entry table row
__device__ inline void decode_prior(int n, int& level, int& S, int& ii, int& jj,
                                    int& aa, int& tb) {
    if (n < 507)        { level = 0; S = 13; int c = n / 3;            aa = n - 3*c;            jj = c % 13; ii = c / 13; tb = 0;   }
    else if (n < 2535)  { level = 1; S = 26; int nn = n - 507;  int c = nn / 3; aa = nn - 3*c; jj = c % 26; ii = c / 26; tb = 39;  }
    else                { level = 2; S = 52; int nn = n - 2535; int c = nn / 3; aa = nn - 3*c; jj = c % 52; ii = c / 52; tb = 117; }
}

// ---------------------------------------------------------------- kernel A
// blocks [0, 800): prior assignment for label gi (unchanged logic).
// blocks [800, 1520): ASSIGN-INDEPENDENT obj-base BCE — per prior:
//   !supp -> BCE(p, 0); chosen-prior corrections are added by kernel B.
// Block 0 also zeroes kernel B's done-counters (ws poisoned each iteration);
// end-of-dispatch release (L2 writeback) publishes them to kernel B.
__global__ __launch_bounds__(256) void assign_obj_kernel(
    const float* __restrict__ o0, const float* __restrict__ o1,
    const float* __restrict__ o2, const float* __restrict__ labels,
    int* __restrict__ idxArr, float4* __restrict__ tcoord,
    double* __restrict__ pObj, int* __restrict__ doneCnt) {
    __shared__ float s_px[273], s_py[273], s_pxe[273], s_pye[273];
    __shared__ float s_iou[NPRI];  // 42.6 KB (assign branch only)
    __shared__ float s_w[4];
    __shared__ int   s_wsum[4];
    __shared__ float s_lbx[LL], s_lby[LL], s_lxe[LL], s_lye[LL], s_lar[LL];
    __shared__ int   s_lcnt;
    __shared__ double s_red[256];

    int tid = threadIdx.x, lane = tid & 63, wid = tid >> 6;
    int gi  = blockIdx.x;
    if (gi == 0 && tid < BB + 1) doneCnt[tid] = 0;   // before any early return

    if (gi < ASS_BLOCKS) {
        // ---------------- assign branch (one block per label) ----------------
        const float* lab = labels + gi * 5;
        float cls = lab[0];
        if (tid == 0) idxArr[gi] = -1;
        if (cls < 0.0f) return;   // uniform per block, before any __syncthreads

        for (int t = tid; t < 273; t += 256) {   // stage constexpr tables to LDS
            s_px[t] = g_ptab.px[t]; s_pxe[t] = g_ptab.pxe[t];
            s_py[t] = g_ptab.py[t]; s_pye[t] = g_ptab.pye[t];
        }
        float bx = lab[1], by = lab[2], bw = lab[3], bh = lab[4];
        float bxe  = __fadd_rn(bx, bw), bye = __fadd_rn(by, bh);
        float bwbh = __fmul_rn(bw, bh);
        __syncthreads();

        float lmax = -3.0e38f;
        for (int n = tid; n < NPRI; n += 256) {
            int level, S, ii, jj, aa, tb;
            decode_prior(n, level, S, ii, jj, aa, tb);
            int tj = tb + aa * S + jj, ti = tb + aa * S + ii;
            float px = s_px[tj], pxe = s_pxe[tj];
            float py = s_py[ti], pye = s_pye[ti];
            float pwph = c_pwph[level][aa];
            float ix = fmaxf(px, bx), iy = fmaxf(py, by);
            float ax = fminf(pxe, bxe), ay = fminf(pye, bye);
            float iw = fmaxf(__fsub_rn(ax, ix), 0.0f);
            float ih = fmaxf(__fsub_rn(ay, iy), 0.0f);
            float inter = __fmul_rn(iw, ih);
            float denom = __fsub_rn(__fadd_rn(pwph, bwbh), inter);
            float iou = __fdiv_rn(inter, denom);
            s_iou[n] = iou;
            lmax = fmaxf(lmax, iou);
        }
        for (int d = 1; d < 64; d <<= 1) lmax = fmaxf(lmax, __shfl_xor(lmax, d));
        if (lane == 0) s_w[wid] = lmax;
        __syncthreads();   // also publishes s_iou
        float m = fmaxf(fmaxf(s_w[0], s_w[1]), fmaxf(s_w[2], s_w[3]));

        const int CH = 42;   // 256*42 >= NPRI
        int start = tid * CH;
        int end   = min(start + CH, NPRI);
        int cnt = 0;
        for (int n = start; n < end; ++n) cnt += (s_iou[n] == m) ? 1 : 0;

        int incl = cnt;
        for (int d = 1; d < 64; d <<= 1) {
            int v = __shfl_up(incl, d);
            if (lane >= d) incl += v;
        }
        if (lane == 63) s_wsum[wid] = incl;
        __syncthreads();
        int woff = 0, k = 0;
        for (int w = 0; w < 4; ++w) { int v = s_wsum[w]; k += v; if (w < wid) woff += v; }
        int rank = (k - 1) / 2 + 1;
        int pre  = woff + incl - cnt;   // exclusive prefix

        if (pre < rank && rank <= pre + cnt) {
            int r = rank - pre;
            int sel = -1;
            for (int n = start; n < end; ++n)
                if (s_iou[n] == m && --r == 0) { sel = n; break; }
            int level, S, ii, jj, aa, tb;
            decode_prior(sel, level, S, ii, jj, aa, tb);
            float Sf = (float)S, colf = (float)jj, rowf = (float)ii;
            float dx = __fsub_rn(__fmul_rn(__fadd_rn(bx, __fmul_rn(0.5f, bw)), Sf), colf);
            float dy = __fsub_rn(__fmul_rn(__fadd_rn(by, __fmul_rn(0.5f, bh)), Sf), rowf);
            dx = fminf(fmaxf(dx, 1e-6f), 0.999999f);
            dy = fminf(fmaxf(dy, 1e-6f), 0.999999f);
            float t0 = logf(__fdiv_rn(dx, __fsub_rn(1.0f, dx)));
            float t1 = logf(__fdiv_rn(dy, __fsub_rn(1.0f, dy)));
            float t2 = logf(__fdiv_rn(__fmul_rn(bw, 416.0f), c_awf[level][aa]));
            float t3 = logf(__fdiv_rn(__fmul_rn(bh, 416.0f), c_ahf[level][aa]));
            tcoord[gi] = make_float4(t0, t1, t2, t3);
            idxArr[gi] = sel;
        }
    } else {
        // ------------- obj-base branch (assign-independent BCE) -------------
        int bid = gi - ASS_BLOCKS;
        int level, m, chunk, S, SS2;
        if (bid < 48)       { level = 0; m = bid;         chunk = 0;           S = 13; SS2 = 169;  }
        else if (bid < 192) { level = 1; int q = bid-48;  m = q / 3;  chunk = q - 3*m;  S = 26; SS2 = 676;  }
        else                { level = 2; int q = bid-192; m = q / 11; chunk = q - 11*m; S = 52; SS2 = 2704; }
        int b  = m / 3;
        int aa = m - 3 * b;
        int pos = chunk * 256 + tid;

        if (tid < S) {   // per-(level,aa) row of the constexpr table
            int tb = ((level == 0) ? 0 : (level == 1) ? 39 : 117) + aa * S;
            s_px[tid]  = g_ptab.px[tb + tid];  s_pxe[tid] = g_ptab.pxe[tb + tid];
            s_py[tid]  = g_ptab.py[tb + tid];  s_pye[tid] = g_ptab.pye[tb + tid];
        }
        if (wid == 0) {   // wave 0 compacts this b's valid labels
            float cls = -1.0f, lbx = 0, lby = 0, lbw = 0, lbh = 0;
            if (lane < LL) {
                const float* lab = labels + (b * LL + lane) * 5;
                cls = lab[0]; lbx = lab[1]; lby = lab[2]; lbw = lab[3]; lbh = lab[4];
            }
            bool valid = (lane < LL) && (cls >= 0.0f);
            unsigned long long mask = __ballot(valid);
            if (valid) {
                int p = __popcll(mask & ((1ull << lane) - 1ull));
                s_lbx[p] = lbx;
                s_lby[p] = lby;
                s_lxe[p] = __fadd_rn(lbx, lbw);
                s_lye[p] = __fadd_rn(lby, lbh);
                s_lar[p] = __fmul_rn(lbw, lbh);
            }
            if (lane == 0) s_lcnt = __popcll(mask);
        }
        __syncthreads();

        double a = 0.0;
        if (pos < SS2) {
            const float* outp = (level == 0) ? o0 : ((level == 1) ? o1 : o2);
            // coalesced: consecutive tid -> consecutive addresses
            float x = outp[((size_t)b * 255 + aa * 85 + 4) * SS2 + pos];
            int ii = pos / S, jj = pos - ii * S;
            float px = s_px[jj], pxe = s_pxe[jj];
            float py = s_py[ii], pye = s_pye[ii];
            float pwph = c_pwph[level][aa];
            bool supp = false;
            int cnt = s_lcnt;
            for (int l = 0; l < cnt; ++l) {   // LDS-broadcast reads, no conflicts
                float ix = fmaxf(px, s_lbx[l]);
                float iy = fmaxf(py, s_lby[l]);
                float ax = fminf(pxe, s_lxe[l]);
                float ay = fminf(pye, s_lye[l]);
                float iw = fmaxf(__fsub_rn(ax, ix), 0.0f);
                float ih = fmaxf(__fsub_rn(ay, iy), 0.0f);
                float inter = __fmul_rn(iw, ih);
                float denom = __fsub_rn(__fadd_rn(pwph, s_lar[l]), inter);
                supp = supp | ((double)inter >= SUPP_C * (double)denom);
            }
            if (!supp) {   // t = 0 path: float expr t*lp+(1-t)*lq == lq exactly
                float p = 1.0f / (1.0f + expf(-x));
                float lq = fmaxf(logf(1.0f - p), -100.0f);
                a = -(double)lq * c_wObj[level];
            }
        }
        s_red[tid] = a; __syncthreads();
        for (int s = 128; s > 0; s >>= 1) { if (tid < s) s_red[tid] += s_red[tid + s]; __syncthreads(); }
        if (tid == 0) pObj[bid] = s_red[0];
    }
}

// ---------------------------------------------------------------- kernel B
// One block per label gi: coord + class + obj correction (as round 3).
// Tail: hierarchical last-block-done finalize replaces the 3rd dispatch.
//   - release: ONLY tid 0 (the sole partial-writer) fences (800 light
//     buffer_wbl2, not 389k like round 2's all-thread version);
//   - counters: 16 per-batch (50 adds each, independent addresses) feeding
//     1 global (16 adds) — no 800-deep same-address serialization;
//   - the globally-last block acquires and reduces in the IDENTICAL fixed
//     order as the old finalize_kernel -> bitwise-same output.
__global__ __launch_bounds__(256) void cho_kernel(
    const float* __restrict__ o0, const float* __restrict__ o1,
    const float* __restrict__ o2, const float* __restrict__ labels,
    const int* __restrict__ idxArr, const float4* __restrict__ tcoord,
    double* __restrict__ pObj,
    double* __restrict__ pCoord, double* __restrict__ pClass,
    double* __restrict__ pCorr, int* __restrict__ doneCnt,
    float* __restrict__ out) {
    __shared__ int    s_cidx[LL];
    __shared__ float  s_ccls[LL];
    __shared__ double s_red[256];
    __shared__ int    s_last;
    int tid = threadIdx.x, lane = tid & 63, wid = tid >> 6;
    int gi = blockIdx.x;
    int b  = gi / LL, lsel = gi - b * LL;

    if (tid < LL) {
        s_cidx[tid] = idxArr[b * LL + tid];
        s_ccls[tid] = labels[(b * LL + tid) * 5];
    }
    __syncthreads();
    int sel = s_cidx[lsel];
    int maxl = -1;
    if (sel >= 0)
        for (int l = 0; l < LL; ++l) if (s_cidx[l] == sel) maxl = l;
    bool active = (sel >= 0) && (maxl == lsel);   // segment_max winner

    double vc = 0.0, vk = 0.0, vcorr = 0.0;
    if (active) {
        int level, S, ii, jj, aa, tb;
        decode_prior(sel, level, S, ii, jj, aa, tb);
        int SS2 = S * S;
        const float* outp = (level == 0) ? o0 : ((level == 1) ? o1 : o2);
        const float* base = outp + (size_t)b * 255 * SS2 + aa * 85 * SS2 + ii * S + jj;
        double wObj = c_wObj[level];
        if (tid < 4) {                     // coord channels 0..3
            float4 ct = tcoord[gi];
            float ctk = (tid == 0) ? ct.x : (tid == 1) ? ct.y : (tid == 2) ? ct.z : ct.w;
            float x = base[tid * SS2];
            float d = __fsub_rn(x, ctk);
            vc = (double)__fmul_rn(d, d) * (wObj * 0.25);
        } else if (tid >= 5 && tid < 85) { // class channels 5..84
            int cc = tid - 5;
            float x = base[tid * SS2];
            float t = 0.0f;
            for (int l = 0; l < LL; ++l)   // multi-hot over ALL labels mapping here
                if (s_cidx[l] == sel && (int)s_ccls[l] == cc) t = 1.0f;
            float p = 1.0f / (1.0f + expf(-x));
            float lp = fmaxf(logf(p), -100.0f);
            float lq = fmaxf(logf(1.0f - p), -100.0f);
            vk = -(double)(t * lp + (1.0f - t) * lq) * (wObj * 0.0125);
        }
        if (wid == 0) {                    // obj correction: supp vote per label
            int tj = tb + aa * S + jj, ti = tb + aa * S + ii;
            float px = g_ptab.px[tj], pxe = g_ptab.pxe[tj];
            float py = g_ptab.py[ti], pye = g_ptab.pye[ti];
            float pwph = c_pwph[level][aa];
            bool vote = false;
            if (lane < LL) {
                const float* lab = labels + (b * LL + lane) * 5;
                if (lab[0] >= 0.0f) {      // same ops as the base supp test
                    float lbx = lab[1], lby = lab[2], lbw = lab[3], lbh = lab[4];
                    float lxe = __fadd_rn(lbx, lbw), lye = __fadd_rn(lby, lbh);
                    float lar = __fmul_rn(lbw, lbh);
                    float ix = fmaxf(px, lbx);
                    float iy = fmaxf(py, lby);
                    float ax = fminf(pxe, lxe);
                    float ay = fminf(pye, lye);
                    float iw = fmaxf(__fsub_rn(ax, ix), 0.0f);
                    float ih = fmaxf(__fsub_rn(ay, iy), 0.0f);
                    float inter = __fmul_rn(iw, ih);
                    float denom = __fsub_rn(__fadd_rn(pwph, lar), inter);
                    vote = ((double)inter >= SUPP_C * (double)denom);
                }
            }
            unsigned long long bal = __ballot(vote);
            if (lane == 0) {
                bool supp = (bal != 0ull);
                float x = base[4 * SS2];
                float p = 1.0f / (1.0f + expf(-x));
                float lp = fmaxf(logf(p), -100.0f);
                float lq = fmaxf(logf(1.0f - p), -100.0f);
                // chosen target - duplicated base term (if base counted it)
                vcorr = -(double)lp * wObj - (supp ? 0.0 : -(double)lq * wObj);
            }
        }
    }
    s_red[tid] = vc; __syncthreads();
    for (int s = 128; s > 0; s >>= 1) { if (tid < s) s_red[tid] += s_red[tid + s]; __syncthreads(); }
    if (tid == 0) pCoord[gi] = s_red[0];
    __syncthreads();
    s_red[tid] = vk; __syncthreads();
    for (int s = 128; s > 0; s >>= 1) { if (tid < s) s_red[tid] += s_red[tid + s]; __syncthreads(); }
    if (tid == 0) { pClass[gi] = s_red[0]; pCorr[gi] = vcorr; }   // vcorr on tid 0

    // ---- hierarchical last-block-done finalize ----
    if (tid == 0) {
        __threadfence();   // release: writeback THIS writer's partials (tid 0 only)
        int done = 0;
        if (atomicAdd(&doneCnt[b], 1) == LL - 1)          // last in batch b
            if (atomicAdd(&doneCnt[BB], 1) == BB - 1)     // last overall
                done = 1;
        s_last = done;
    }
    __syncthreads();
    if (s_last) {
        __threadfence();   // acquire: invalidate L2 so re-reads hit memory
        const volatile double* vO = pObj;
        const volatile double* vR = pCorr;
        const volatile double* vC = pCoord;
        const volatile double* vK = pClass;
        double sO = 0.0, sC = 0.0, sK = 0.0;
        for (int i = tid; i < OBJ_BLOCKS; i += 256) sO += vO[i];
        for (int i = tid; i < CHO_BLOCKS; i += 256) { sO += vR[i]; sC += vC[i]; sK += vK[i]; }
        s_red[tid] = sO; __syncthreads();
        for (int s = 128; s > 0; s >>= 1) { if (tid < s) s_red[tid] += s_red[tid + s]; __syncthreads(); }
        if (tid == 0) out[0] = (float)s_red[0];
        __syncthreads();
        s_red[tid] = sC; __syncthreads();
        for (int s = 128; s > 0; s >>= 1) { if (tid < s) s_red[tid] += s_red[tid + s]; __syncthreads(); }
        if (tid == 0) out[1] = (float)s_red[0];
        __syncthreads();
        s_red[tid] = sK; __syncthreads();
        for (int s = 128; s > 0; s >>= 1) { if (tid < s) s_red[tid] += s_red[tid + s]; __syncthreads(); }
        if (tid == 0) out[2] = (float)s_red[0];
    }
}

extern "C" void kernel_launch(void* const* d_in, const int* in_sizes, int n_in,
                              void* d_out, int out_size, void* d_ws, size_t ws_size,
                              hipStream_t stream) {
    const float* o0     = (const float*)d_in[0];
    const float* o1     = (const float*)d_in[1];
    const float* o2     = (const float*)d_in[2];
    const float* labels = (const float*)d_in[3];

    char* ws = (char*)d_ws;
    int*    idxArr  = (int*)   (ws);          // 800*4  = 3200
    float4* tcoord  = (float4*)(ws + 3200);   // 800*16 -> 16000
    double* pObj    = (double*)(ws + 16000);  // 720*8  -> 21760
    double* pCoord  = (double*)(ws + 21760);  // 800*8  -> 28160
    double* pClass  = (double*)(ws + 28160);  // 800*8  -> 34560
    double* pCorr   = (double*)(ws + 34560);  // 800*8  -> 40960
    int*    doneCnt = (int*)   (ws + 40960);  // 17*4   -> 41028 (16 batch + 1 global)

    assign_obj_kernel<<<A_BLOCKS, 256, 0, stream>>>(o0, o1, o2, labels,
                                                    idxArr, tcoord, pObj, doneCnt);
    cho_kernel<<<CHO_BLOCKS, 256, 0, stream>>>(o0, o1, o2, labels, idxArr, tcoord,
                                               pObj, pCoord, pClass, pCorr,
                                               doneCnt, (float*)d_out);
}

// Round 5
// 119.591 us; speedup vs baseline: 1.1638x; 1.1638x over previous
//
#include <hip/hip_runtime.h>

#define NPRI 10647
#define BB 16
#define LL 50
#define ASS_BLOCKS (BB * LL)                 // 800 assign blocks (one per label)
#define OBJ_BLOCKS 720                       // 48 (L0) + 144 (L1) + 528 (L2)
#define A_BLOCKS (ASS_BLOCKS + OBJ_BLOCKS)   // 1520: fused assign + obj-base
#define CHO_BLOCKS (BB * LL)                 // 800

// 0.5 - 2^-26: exact post-rounding threshold. round_rn(inter/denom) >= 0.5f
// <=> inter >= denom * SUPP_C (significand product exact in double; tie at
// 0.5-2^-26 rounds to even = 0.5 => suppressed). Validated earlier sessions.
#define SUPP_C 0.49999998509883880615234375

// ---- compile-time anchor constants (numpy python-float math) ----
constexpr double HWd[3][3] = {
    {0.5*(116.0/416.0), 0.5*(156.0/416.0), 0.5*(373.0/416.0)},
    {0.5*( 30.0/416.0), 0.5*( 62.0/416.0), 0.5*( 59.0/416.0)},
    {0.5*( 10.0/416.0), 0.5*( 16.0/416.0), 0.5*( 33.0/416.0)}};
constexpr double HHd[3][3] = {
    {0.5*( 90.0/416.0), 0.5*(198.0/416.0), 0.5*(326.0/416.0)},
    {0.5*( 61.0/416.0), 0.5*( 45.0/416.0), 0.5*(119.0/416.0)},
    {0.5*( 23.0/416.0), 0.5*( 30.0/416.0), 0.5*( 23.0/416.0)}};
constexpr float PWf[3][3] = {
    {(float)(116.0/416.0), (float)(156.0/416.0), (float)(373.0/416.0)},
    {(float)( 30.0/416.0), (float)( 62.0/416.0), (float)( 59.0/416.0)},
    {(float)( 10.0/416.0), (float)( 16.0/416.0), (float)( 33.0/416.0)}};
constexpr float PHf[3][3] = {
    {(float)( 90.0/416.0), (float)(198.0/416.0), (float)(326.0/416.0)},
    {(float)( 61.0/416.0), (float)( 45.0/416.0), (float)(119.0/416.0)},
    {(float)( 23.0/416.0), (float)( 30.0/416.0), (float)( 23.0/416.0)}};

// Entire 273-entry (level,aa,idx) prior table baked at COMPILE TIME — clang
// constexpr fp math is IEEE RN, bitwise-identical to the old runtime
// f64-div + __fadd_rn sequence. No runtime f64 divides remain anywhere.
struct PTab { float px[273], pxe[273], py[273], pye[273]; };
constexpr PTab make_ptab() {
    PTab t{};
    for (int tt = 0; tt < 273; ++tt) {
        int level, aa, idx;
        if (tt < 39)       { level = 0; aa = tt / 13;           idx = tt - 13 * aa; }
        else if (tt < 117) { level = 1; int q = tt - 39;  aa = q / 26; idx = q - 26 * aa; }
        else               { level = 2; int q = tt - 117; aa = q / 52; idx = q - 52 * aa; }
        int S = (level == 0) ? 13 : (level == 1) ? 26 : 52;
        double c = ((double)idx + 0.5) / (double)S;   // numpy-exact
        float px = (float)(c - HWd[level][aa]);
        float py = (float)(c - HHd[level][aa]);
        t.px[tt] = px; t.pxe[tt] = px + PWf[level][aa];
        t.py[tt] = py; t.pye[tt] = py + PHf[level][aa];
    }
    return t;
}
__device__ __constant__ PTab g_ptab = make_ptab();

// pw*ph folded at compile time (float x float, IEEE RN == __fmul_rn)
__device__ __constant__ float c_pwph[3][3] = {
    {(float)(116.0/416.0)*(float)( 90.0/416.0), (float)(156.0/416.0)*(float)(198.0/416.0), (float)(373.0/416.0)*(float)(326.0/416.0)},
    {(float)( 30.0/416.0)*(float)( 61.0/416.0), (float)( 62.0/416.0)*(float)( 45.0/416.0), (float)( 59.0/416.0)*(float)(119.0/416.0)},
    {(float)( 10.0/416.0)*(float)( 23.0/416.0), (float)( 16.0/416.0)*(float)( 30.0/416.0), (float)( 33.0/416.0)*(float)( 23.0/416.0)}};
__device__ __constant__ float c_awf[3][3] = {{116,156,373},{30,62,59},{10,16,33}};
__device__ __constant__ float c_ahf[3][3] = {{90,198,326},{61,45,119},{23,30,23}};
// 1 / (B*A*S*S) per level
__device__ __constant__ double c_wObj[3] = {1.0/8112.0, 1.0/32448.0, 1.0/129792.0};

// decode prior n -> level,S,ii,jj,aa and base of the 273-entry table row
__device__ inline void decode_prior(int n, int& level, int& S, int& ii, int& jj,
                                    int& aa, int& tb) {
    if (n < 507)        { level = 0; S = 13; int c = n / 3;            aa = n - 3*c;            jj = c % 13; ii = c / 13; tb = 0;   }
    else if (n < 2535)  { level = 1; S = 26; int nn = n - 507;  int c = nn / 3; aa = nn - 3*c; jj = c % 26; ii = c / 26; tb = 39;  }
    else                { level = 2; S = 52; int nn = n - 2535; int c = nn / 3; aa = nn - 3*c; jj = c % 52; ii = c / 52; tb = 117; }
}

// ---------------------------------------------------------------- kernel A
// blocks [0, 800): prior assignment for label gi (unchanged logic).
// blocks [800, 1520): ASSIGN-INDEPENDENT obj-base BCE — per prior:
//   !supp -> BCE(p, 0); chosen-prior corrections are added by kernel B.
// Fusing these lets the 1.5 MB activation read overlap the assign compute.
__global__ __launch_bounds__(256) void assign_obj_kernel(
    const float* __restrict__ o0, const float* __restrict__ o1,
    const float* __restrict__ o2, const float* __restrict__ labels,
    int* __restrict__ idxArr, float4* __restrict__ tcoord,
    double* __restrict__ pObj) {
    __shared__ float s_px[273], s_py[273], s_pxe[273], s_pye[273];
    __shared__ float s_iou[NPRI];  // 42.6 KB (assign branch only)
    __shared__ float s_w[4];
    __shared__ int   s_wsum[4];
    __shared__ float s_lbx[LL], s_lby[LL], s_lxe[LL], s_lye[LL], s_lar[LL];
    __shared__ int   s_lcnt;
    __shared__ double s_red[256];

    int tid = threadIdx.x, lane = tid & 63, wid = tid >> 6;
    int gi  = blockIdx.x;

    if (gi < ASS_BLOCKS) {
        // ---------------- assign branch (one block per label) ----------------
        const float* lab = labels + gi * 5;
        float cls = lab[0];
        if (tid == 0) idxArr[gi] = -1;
        if (cls < 0.0f) return;   // uniform per block, before any __syncthreads

        for (int t = tid; t < 273; t += 256) {   // stage constexpr tables to LDS
            s_px[t] = g_ptab.px[t]; s_pxe[t] = g_ptab.pxe[t];
            s_py[t] = g_ptab.py[t]; s_pye[t] = g_ptab.pye[t];
        }
        float bx = lab[1], by = lab[2], bw = lab[3], bh = lab[4];
        float bxe  = __fadd_rn(bx, bw), bye = __fadd_rn(by, bh);
        float bwbh = __fmul_rn(bw, bh);
        __syncthreads();

        float lmax = -3.0e38f;
        for (int n = tid; n < NPRI; n += 256) {
            int level, S, ii, jj, aa, tb;
            decode_prior(n, level, S, ii, jj, aa, tb);
            int tj = tb + aa * S + jj, ti = tb + aa * S + ii;
            float px = s_px[tj], pxe = s_pxe[tj];
            float py = s_py[ti], pye = s_pye[ti];
            float pwph = c_pwph[level][aa];
            float ix = fmaxf(px, bx), iy = fmaxf(py, by);
            float ax = fminf(pxe, bxe), ay = fminf(pye, bye);
            float iw = fmaxf(__fsub_rn(ax, ix), 0.0f);
            float ih = fmaxf(__fsub_rn(ay, iy), 0.0f);
            float inter = __fmul_rn(iw, ih);
            float denom = __fsub_rn(__fadd_rn(pwph, bwbh), inter);
            float iou = __fdiv_rn(inter, denom);
            s_iou[n] = iou;
            lmax = fmaxf(lmax, iou);
        }
        for (int d = 1; d < 64; d <<= 1) lmax = fmaxf(lmax, __shfl_xor(lmax, d));
        if (lane == 0) s_w[wid] = lmax;
        __syncthreads();   // also publishes s_iou
        float m = fmaxf(fmaxf(s_w[0], s_w[1]), fmaxf(s_w[2], s_w[3]));

        const int CH = 42;   // 256*42 >= NPRI
        int start = tid * CH;
        int end   = min(start + CH, NPRI);
        int cnt = 0;
        for (int n = start; n < end; ++n) cnt += (s_iou[n] == m) ? 1 : 0;

        int incl = cnt;
        for (int d = 1; d < 64; d <<= 1) {
            int v = __shfl_up(incl, d);
            if (lane >= d) incl += v;
        }
        if (lane == 63) s_wsum[wid] = incl;
        __syncthreads();
        int woff = 0, k = 0;
        for (int w = 0; w < 4; ++w) { int v = s_wsum[w]; k += v; if (w < wid) woff += v; }
        int rank = (k - 1) / 2 + 1;
        int pre  = woff + incl - cnt;   // exclusive prefix

        if (pre < rank && rank <= pre + cnt) {
            int r = rank - pre;
            int sel = -1;
            for (int n = start; n < end; ++n)
                if (s_iou[n] == m && --r == 0) { sel = n; break; }
            int level, S, ii, jj, aa, tb;
            decode_prior(sel, level, S, ii, jj, aa, tb);
            float Sf = (float)S, colf = (float)jj, rowf = (float)ii;
            float dx = __fsub_rn(__fmul_rn(__fadd_rn(bx, __fmul_rn(0.5f, bw)), Sf), colf);
            float dy = __fsub_rn(__fmul_rn(__fadd_rn(by, __fmul_rn(0.5f, bh)), Sf), rowf);
            dx = fminf(fmaxf(dx, 1e-6f), 0.999999f);
            dy = fminf(fmaxf(dy, 1e-6f), 0.999999f);
            float t0 = logf(__fdiv_rn(dx, __fsub_rn(1.0f, dx)));
            float t1 = logf(__fdiv_rn(dy, __fsub_rn(1.0f, dy)));
            float t2 = logf(__fdiv_rn(__fmul_rn(bw, 416.0f), c_awf[level][aa]));
            float t3 = logf(__fdiv_rn(__fmul_rn(bh, 416.0f), c_ahf[level][aa]));
            tcoord[gi] = make_float4(t0, t1, t2, t3);
            idxArr[gi] = sel;
        }
    } else {
        // ------------- obj-base branch (assign-independent BCE) -------------
        int bid = gi - ASS_BLOCKS;
        int level, m, chunk, S, SS2;
        if (bid < 48)       { level = 0; m = bid;         chunk = 0;           S = 13; SS2 = 169;  }
        else if (bid < 192) { level = 1; int q = bid-48;  m = q / 3;  chunk = q - 3*m;  S = 26; SS2 = 676;  }
        else                { level = 2; int q = bid-192; m = q / 11; chunk = q - 11*m; S = 52; SS2 = 2704; }
        int b  = m / 3;
        int aa = m - 3 * b;
        int pos = chunk * 256 + tid;

        if (tid < S) {   // per-(level,aa) row of the constexpr table
            int tb = ((level == 0) ? 0 : (level == 1) ? 39 : 117) + aa * S;
            s_px[tid]  = g_ptab.px[tb + tid];  s_pxe[tid] = g_ptab.pxe[tb + tid];
            s_py[tid]  = g_ptab.py[tb + tid];  s_pye[tid] = g_ptab.pye[tb + tid];
        }
        if (wid == 0) {   // wave 0 compacts this b's valid labels
            float cls = -1.0f, lbx = 0, lby = 0, lbw = 0, lbh = 0;
            if (lane < LL) {
                const float* lab = labels + (b * LL + lane) * 5;
                cls = lab[0]; lbx = lab[1]; lby = lab[2]; lbw = lab[3]; lbh = lab[4];
            }
            bool valid = (lane < LL) && (cls >= 0.0f);
            unsigned long long mask = __ballot(valid);
            if (valid) {
                int p = __popcll(mask & ((1ull << lane) - 1ull));
                s_lbx[p] = lbx;
                s_lby[p] = lby;
                s_lxe[p] = __fadd_rn(lbx, lbw);
                s_lye[p] = __fadd_rn(lby, lbh);
                s_lar[p] = __fmul_rn(lbw, lbh);
            }
            if (lane == 0) s_lcnt = __popcll(mask);
        }
        __syncthreads();

        double a = 0.0;
        if (pos < SS2) {
            const float* outp = (level == 0) ? o0 : ((level == 1) ? o1 : o2);
            // coalesced: consecutive tid -> consecutive addresses
            float x = outp[((size_t)b * 255 + aa * 85 + 4) * SS2 + pos];
            int ii = pos / S, jj = pos - ii * S;
            float px = s_px[jj], pxe = s_pxe[jj];
            float py = s_py[ii], pye = s_pye[ii];
            float pwph = c_pwph[level][aa];
            bool supp = false;
            int cnt = s_lcnt;
            for (int l = 0; l < cnt; ++l) {   // LDS-broadcast reads, no conflicts
                float ix = fmaxf(px, s_lbx[l]);
                float iy = fmaxf(py, s_lby[l]);
                float ax = fminf(pxe, s_lxe[l]);
                float ay = fminf(pye, s_lye[l]);
                float iw = fmaxf(__fsub_rn(ax, ix), 0.0f);
                float ih = fmaxf(__fsub_rn(ay, iy), 0.0f);
                float inter = __fmul_rn(iw, ih);
                float denom = __fsub_rn(__fadd_rn(pwph, s_lar[l]), inter);
                supp = supp | ((double)inter >= SUPP_C * (double)denom);
            }
            if (!supp) {   // t = 0 path: float expr t*lp+(1-t)*lq == lq exactly
                float p = 1.0f / (1.0f + expf(-x));
                float lq = fmaxf(logf(1.0f - p), -100.0f);
                a = -(double)lq * c_wObj[level];
            }
        }
        s_red[tid] = a; __syncthreads();
        for (int s = 128; s > 0; s >>= 1) { if (tid < s) s_red[tid] += s_red[tid + s]; __syncthreads(); }
        if (tid == 0) pObj[bid] = s_red[0];
    }
}

// ---------------------------------------------------------------- kernel B
// One block per label gi: coord + class (as before) PLUS the obj correction
// for this label's won prior: corr = BCE(p,1) - (!supp ? BCE(p,0) : 0),
// with supp recomputed using bitwise-identical float ops vs the base branch.
__global__ __launch_bounds__(256) void cho_kernel(
    const float* __restrict__ o0, const float* __restrict__ o1,
    const float* __restrict__ o2, const float* __restrict__ labels,
    const int* __restrict__ idxArr, const float4* __restrict__ tcoord,
    double* __restrict__ pCoord, double* __restrict__ pClass,
    double* __restrict__ pCorr) {
    __shared__ int    s_cidx[LL];
    __shared__ float  s_ccls[LL];
    __shared__ double s_red[256];
    int tid = threadIdx.x, lane = tid & 63, wid = tid >> 6;
    int gi = blockIdx.x;
    int b  = gi / LL, lsel = gi - b * LL;

    if (tid < LL) {
        s_cidx[tid] = idxArr[b * LL + tid];
        s_ccls[tid] = labels[(b * LL + tid) * 5];
    }
    __syncthreads();
    int sel = s_cidx[lsel];
    int maxl = -1;
    if (sel >= 0)
        for (int l = 0; l < LL; ++l) if (s_cidx[l] == sel) maxl = l;
    bool active = (sel >= 0) && (maxl == lsel);   // segment_max winner

    double vc = 0.0, vk = 0.0, vcorr = 0.0;
    if (active) {
        int level, S, ii, jj, aa, tb;
        decode_prior(sel, level, S, ii, jj, aa, tb);
        int SS2 = S * S;
        const float* outp = (level == 0) ? o0 : ((level == 1) ? o1 : o2);
        const float* base = outp + (size_t)b * 255 * SS2 + aa * 85 * SS2 + ii * S + jj;
        double wObj = c_wObj[level];
        if (tid < 4) {                     // coord channels 0..3
            float4 ct = tcoord[gi];
            float ctk = (tid == 0) ? ct.x : (tid == 1) ? ct.y : (tid == 2) ? ct.z : ct.w;
            float x = base[tid * SS2];
            float d = __fsub_rn(x, ctk);
            vc = (double)__fmul_rn(d, d) * (wObj * 0.25);
        } else if (tid >= 5 && tid < 85) { // class channels 5..84
            int cc = tid - 5;
            float x = base[tid * SS2];
            float t = 0.0f;
            for (int l = 0; l < LL; ++l)   // multi-hot over ALL labels mapping here
                if (s_cidx[l] == sel && (int)s_ccls[l] == cc) t = 1.0f;
            float p = 1.0f / (1.0f + expf(-x));
            float lp = fmaxf(logf(p), -100.0f);
            float lq = fmaxf(logf(1.0f - p), -100.0f);
            vk = -(double)(t * lp + (1.0f - t) * lq) * (wObj * 0.0125);
        }
        if (wid == 0) {                    // obj correction: supp vote per label
            int tj = tb + aa * S + jj, ti = tb + aa * S + ii;
            float px = g_ptab.px[tj], pxe = g_ptab.pxe[tj];
            float py = g_ptab.py[ti], pye = g_ptab.pye[ti];
            float pwph = c_pwph[level][aa];
            bool vote = false;
            if (lane < LL) {
                const float* lab = labels + (b * LL + lane) * 5;
                if (lab[0] >= 0.0f) {      // same ops as the base supp test
                    float lbx = lab[1], lby = lab[2], lbw = lab[3], lbh = lab[4];
                    float lxe = __fadd_rn(lbx, lbw), lye = __fadd_rn(lby, lbh);
                    float lar = __fmul_rn(lbw, lbh);
                    float ix = fmaxf(px, lbx);
                    float iy = fmaxf(py, lby);
                    float ax = fminf(pxe, lxe);
                    float ay = fminf(pye, lye);
                    float iw = fmaxf(__fsub_rn(ax, ix), 0.0f);
                    float ih = fmaxf(__fsub_rn(ay, iy), 0.0f);
                    float inter = __fmul_rn(iw, ih);
                    float denom = __fsub_rn(__fadd_rn(pwph, lar), inter);
                    vote = ((double)inter >= SUPP_C * (double)denom);
                }
            }
            unsigned long long bal = __ballot(vote);
            if (lane == 0) {
                bool supp = (bal != 0ull);
                float x = base[4 * SS2];
                float p = 1.0f / (1.0f + expf(-x));
                float lp = fmaxf(logf(p), -100.0f);
                float lq = fmaxf(logf(1.0f - p), -100.0f);
                // chosen target - duplicated base term (if base counted it)
                vcorr = -(double)lp * wObj - (supp ? 0.0 : -(double)lq * wObj);
            }
        }
    }
    s_red[tid] = vc; __syncthreads();
    for (int s = 128; s > 0; s >>= 1) { if (tid < s) s_red[tid] += s_red[tid + s]; __syncthreads(); }
    if (tid == 0) pCoord[gi] = s_red[0];
    __syncthreads();
    s_red[tid] = vk; __syncthreads();
    for (int s = 128; s > 0; s >>= 1) { if (tid < s) s_red[tid] += s_red[tid + s]; __syncthreads(); }
    if (tid == 0) { pClass[gi] = s_red[0]; pCorr[gi] = vcorr; }   // vcorr lives on tid 0
}

// ---------------------------------------------------------------- finalize (1 block, no atomics)
__global__ __launch_bounds__(256) void finalize_kernel(
    const double* __restrict__ pObj, const double* __restrict__ pCorr,
    const double* __restrict__ pCoord, const double* __restrict__ pClass,
    float* __restrict__ out) {
    int tid = threadIdx.x;
    double sO = 0.0, sC = 0.0, sK = 0.0;
    for (int i = tid; i < OBJ_BLOCKS; i += 256) sO += pObj[i];
    for (int i = tid; i < CHO_BLOCKS; i += 256) { sO += pCorr[i]; sC += pCoord[i]; sK += pClass[i]; }
    __shared__ double r0[256], r1[256], r2[256];
    r0[tid] = sO; r1[tid] = sC; r2[tid] = sK;
    __syncthreads();
    for (int s = 128; s > 0; s >>= 1) {
        if (tid < s) { r0[tid] += r0[tid + s]; r1[tid] += r1[tid + s]; r2[tid] += r2[tid + s]; }
        __syncthreads();
    }
    if (tid == 0) { out[0] = (float)r0[0]; out[1] = (float)r1[0]; out[2] = (float)r2[0]; }
}

extern "C" void kernel_launch(void* const* d_in, const int* in_sizes, int n_in,
                              void* d_out, int out_size, void* d_ws, size_t ws_size,
                              hipStream_t stream) {
    const float* o0     = (const float*)d_in[0];
    const float* o1     = (const float*)d_in[1];
    const float* o2     = (const float*)d_in[2];
    const float* labels = (const float*)d_in[3];

    char* ws = (char*)d_ws;
    int*    idxArr = (int*)   (ws);          // 800*4  = 3200
    float4* tcoord = (float4*)(ws + 3200);   // 800*16 -> 16000
    double* pObj   = (double*)(ws + 16000);  // 720*8  -> 21760
    double* pCoord = (double*)(ws + 21760);  // 800*8  -> 28160
    double* pClass = (double*)(ws + 28160);  // 800*8  -> 34560
    double* pCorr  = (double*)(ws + 34560);  // 800*8  -> 40960

    assign_obj_kernel<<<A_BLOCKS, 256, 0, stream>>>(o0, o1, o2, labels,
                                                    idxArr, tcoord, pObj);
    cho_kernel<<<CHO_BLOCKS, 256, 0, stream>>>(o0, o1, o2, labels, idxArr, tcoord,
                                               pCoord, pClass, pCorr);
    finalize_kernel<<<1, 256, 0, stream>>>(pObj, pCorr, pCoord, pClass,
                                           (float*)d_out);
}